// Round 12
// baseline (421.467 us; speedup 1.0000x reference)
//
#include <hip/hip_runtime.h>

#define EPSN 1e-12f
#define SCALE_F 0.044194173824159216f  // 512^-0.5
#define MTOT 50176

typedef __bf16 bf16x8 __attribute__((ext_vector_type(8)));
typedef float  f32x4  __attribute__((ext_vector_type(4)));

__device__ __forceinline__ void gld16(const void* src, void* dst) {
  __builtin_amdgcn_global_load_lds(
      (const __attribute__((address_space(1))) unsigned int*)src,
      (__attribute__((address_space(3))) unsigned int*)dst, 16, 0, 0);
}

// ---------------- prep: xT[bl][n][c] = bf16(x[b0+bl][c][n]) ----------------
__global__ __launch_bounds__(256) void k_xt(const float* __restrict__ x,
                                            __bf16* __restrict__ xT, int b0) {
  __shared__ float T[32][33];
  const int n0 = blockIdx.x * 32, c0 = blockIdx.y * 32;
  const int bl = blockIdx.z, b = b0 + bl;
  const int dx = threadIdx.x, ty = threadIdx.y;   // 32, 8
  #pragma unroll
  for (int pp = 0; pp < 4; ++pp) {
    int c = ty + pp * 8;
    int n = n0 + dx;
    T[c][dx] = (n < 784) ? x[((size_t)b * 512 + c0 + c) * 784 + n] : 0.f;
  }
  __syncthreads();
  #pragma unroll
  for (int pp = 0; pp < 4; ++pp) {
    int n = ty + pp * 8;
    if (n0 + n < 784)
      xT[((size_t)bl * 784 + n0 + n) * 512 + c0 + dx] = (__bf16)T[dx][n];
  }
}

// ---------------- prep: WqT/WkT bf16 [d][c] = W[c][d], LDS tile transpose ----------------
__global__ __launch_bounds__(256) void k_prep_t(const float* __restrict__ Wq,
                                                const float* __restrict__ Wk,
                                                __bf16* __restrict__ WqT,
                                                __bf16* __restrict__ WkT) {
  __shared__ float Tq[32][33], Tk[32][33];
  const int c0 = blockIdx.x * 32, d0 = blockIdx.y * 32;
  const int dx = threadIdx.x, cy = threadIdx.y;  // 32, 8
  #pragma unroll
  for (int p = 0; p < 4; ++p) {
    int c = cy + p * 8;
    Tq[c][dx] = Wq[(size_t)(c0 + c) * 512 + d0 + dx];
    Tk[c][dx] = Wk[(size_t)(c0 + c) * 512 + d0 + dx];
  }
  __syncthreads();
  #pragma unroll
  for (int p = 0; p < 4; ++p) {
    int d = cy + p * 8;
    WqT[(size_t)(d0 + d) * 512 + c0 + dx] = (__bf16)Tq[dx][d];
    WkT[(size_t)(d0 + d) * 512 + c0 + dx] = (__bf16)Tk[dx][d];
  }
}

// ---- prep: WcT[d][kk]: kk<512 -> (Wp@Wf)[kk][d]; kk>=512 -> Wf[kk-512][d]. bpf[d]=bp@Wf+bf
__global__ __launch_bounds__(512) void k_prep_w(const float* __restrict__ Wp,
                                                const float* __restrict__ Wf,
                                                const float* __restrict__ bp,
                                                const float* __restrict__ bfv,
                                                __bf16* __restrict__ WcT,
                                                float* __restrict__ bpf) {
  const int kk0 = blockIdx.x * 2;
  const int d = threadIdx.x;
  float acc0 = 0.f, acc1 = 0.f, bacc = 0.f;
  const bool dobp = (blockIdx.x == 0);
  for (int c = 0; c < 512; ++c) {
    float wf = Wf[(size_t)c * 512 + d];
    acc0 = fmaf(Wp[(size_t)kk0 * 512 + c],       wf, acc0);
    acc1 = fmaf(Wp[(size_t)(kk0 + 1) * 512 + c], wf, acc1);
    if (dobp) bacc = fmaf(bp[c], wf, bacc);
  }
  WcT[(size_t)d * 1024 + kk0]           = (__bf16)acc0;
  WcT[(size_t)d * 1024 + kk0 + 1]       = (__bf16)acc1;
  WcT[(size_t)d * 1024 + 512 + kk0]     = (__bf16)Wf[(size_t)kk0 * 512 + d];
  WcT[(size_t)d * 1024 + 512 + kk0 + 1] = (__bf16)Wf[(size_t)(kk0 + 1) * 512 + d];
  if (dobp) bpf[d] = bacc + bfv[d];
}

// ---------------- merged Q+K GEMM: 128x128, all-gld16, RING-3 depth-2 ----------------
__global__ __launch_bounds__(256, 2) void k_gemm(const __bf16* __restrict__ xT,
                                                 const __bf16* __restrict__ WqT,
                                                 const __bf16* __restrict__ WkT,
                                                 const float* __restrict__ bq,
                                                 const float* __restrict__ bk,
                                                 const float* __restrict__ wg,
                                                 const int b0,
                                                 __bf16* __restrict__ qraw,
                                                 __bf16* __restrict__ kraw,
                                                 float* __restrict__ psqQ,
                                                 float* __restrict__ psqK,
                                                 float* __restrict__ gdo) {
  __shared__ __align__(1024) unsigned char stg[3][24576];   // As 8K | BQs 8K | BKs 8K
  const int t = threadIdx.x, l = t & 63, w = t >> 6;
  const int li = l & 15, lq = l >> 4;
  const int p = blockIdx.x;
  const int xq = p & 7, q2 = p >> 3;
  const int nt = q2 & 3;
  const int g = (q2 >> 2) * 8 + xq;       // 0..223
  const int bl = g / 7, mt = g % 7;
  const int b = b0 + bl;
  const int m0 = mt * 128;

  const int r0 = 2 * w, r1 = r0 + 1;
  int row0 = m0 + r0 * 16 + li; if (row0 > 783) row0 = 783;
  int row1 = m0 + r1 * 16 + li; if (row1 > 783) row1 = 783;
  const __bf16* a0s = xT + ((size_t)bl * 784 + row0) * 512 + lq * 8;
  const __bf16* a1s = xT + ((size_t)bl * 784 + row1) * 512 + lq * 8;
  const __bf16* q0s = WqT + (size_t)(nt * 128 + r0 * 16 + li) * 512 + lq * 8;
  const __bf16* q1s = WqT + (size_t)(nt * 128 + r1 * 16 + li) * 512 + lq * 8;
  const __bf16* k0s = WkT + (size_t)(nt * 128 + r0 * 16 + li) * 512 + lq * 8;
  const __bf16* k1s = WkT + (size_t)(nt * 128 + r1 * 16 + li) * 512 + lq * 8;

  f32x4 accQ[4][4] = {}, accK[4][4] = {};

  auto stage = [&](unsigned char* buf, int ks) {
    const int kk = (ks > 15 ? 15 : ks) * 32;
    gld16(a0s + kk, buf + r0 * 1024);
    gld16(a1s + kk, buf + r1 * 1024);
    gld16(q0s + kk, buf + 8192 + r0 * 1024);
    gld16(q1s + kk, buf + 8192 + r1 * 1024);
    gld16(k0s + kk, buf + 16384 + r0 * 1024);
    gld16(k1s + kk, buf + 16384 + r1 * 1024);
  };
  auto mstep = [&](const unsigned char* buf) {
    bf16x8 af[4];
    #pragma unroll
    for (int rb = 0; rb < 4; ++rb)
      af[rb] = *(const bf16x8*)(buf + ((w & 1) * 4 + rb) * 1024 + l * 16);
    #pragma unroll
    for (int cb = 0; cb < 4; ++cb) {
      bf16x8 bq8 = *(const bf16x8*)(buf + 8192 + ((w >> 1) * 4 + cb) * 1024 + l * 16);
      #pragma unroll
      for (int rb = 0; rb < 4; ++rb)
        accQ[rb][cb] = __builtin_amdgcn_mfma_f32_16x16x32_bf16(af[rb], bq8, accQ[rb][cb], 0, 0, 0);
      bf16x8 bk8 = *(const bf16x8*)(buf + 16384 + ((w >> 1) * 4 + cb) * 1024 + l * 16);
      #pragma unroll
      for (int rb = 0; rb < 4; ++rb)
        accK[rb][cb] = __builtin_amdgcn_mfma_f32_16x16x32_bf16(af[rb], bk8, accK[rb][cb], 0, 0, 0);
    }
  };

  unsigned char *bc = stg[0], *bn = stg[1], *bn2 = stg[2];
  stage(bc, 0); stage(bn, 1);                               // 12 ops in flight
  asm volatile("s_waitcnt vmcnt(6)" ::: "memory");          // tile 0 landed
  __builtin_amdgcn_s_barrier();
  __builtin_amdgcn_sched_barrier(0);
  #pragma unroll 1
  for (int ks = 0; ks < 16; ++ks) {
    stage(bn2, ks + 2);                      // issue tile k+2 (clamped tail)
    __builtin_amdgcn_sched_barrier(0);
    mstep(bc);                               // compute tile k
    asm volatile("s_waitcnt vmcnt(6)" ::: "memory");  // retire tile k+1; k+2 stays in flight
    __builtin_amdgcn_s_barrier();
    __builtin_amdgcn_sched_barrier(0);
    unsigned char* tmp = bc; bc = bn; bn = bn2; bn2 = tmp;
  }
  asm volatile("s_waitcnt vmcnt(0)" ::: "memory");

  // epilogue: bias, raw stores, per-colgroup partial sumsq (Q,K) + gdot (Q)
  const int colb = nt * 128 + (w >> 1) * 64;
  const int cg = nt * 2 + (w >> 1);
  float bqv[4], bkv[4], wv[4];
  #pragma unroll
  for (int cb = 0; cb < 4; ++cb) {
    int col = colb + cb * 16 + li;
    bqv[cb] = bq[col]; bkv[cb] = bk[col]; wv[cb] = wg[col];
  }
  #pragma unroll
  for (int rb = 0; rb < 4; ++rb)
    #pragma unroll
    for (int j = 0; j < 4; ++j) {
      int rowg = m0 + (w & 1) * 64 + rb * 16 + lq * 4 + j;
      bool ok = rowg < 784;
      size_t token = (size_t)b * 784 + rowg;
      float ssq = 0.f, ssk = 0.f, sg = 0.f;
      #pragma unroll
      for (int cb = 0; cb < 4; ++cb) {
        float vq = accQ[rb][cb][j] + bqv[cb];
        float vk = accK[rb][cb][j] + bkv[cb];
        ssq = fmaf(vq, vq, ssq);
        ssk = fmaf(vk, vk, ssk);
        sg  = fmaf(vq, wv[cb], sg);
        if (ok) {
          qraw[token * 512 + colb + cb * 16 + li] = (__bf16)vq;
          kraw[token * 512 + colb + cb * 16 + li] = (__bf16)vk;
        }
      }
      ssq += __shfl_xor(ssq, 1); ssq += __shfl_xor(ssq, 2); ssq += __shfl_xor(ssq, 4); ssq += __shfl_xor(ssq, 8);
      ssk += __shfl_xor(ssk, 1); ssk += __shfl_xor(ssk, 2); ssk += __shfl_xor(ssk, 4); ssk += __shfl_xor(ssk, 8);
      sg  += __shfl_xor(sg, 1);  sg  += __shfl_xor(sg, 2);  sg  += __shfl_xor(sg, 4);  sg  += __shfl_xor(sg, 8);
      if (ok && li == 0) {
        psqQ[(size_t)cg * MTOT + token] = ssq;
        psqK[(size_t)cg * MTOT + token] = ssk;
        gdo [(size_t)cg * MTOT + token] = sg;
      }
    }
}

// ---------------- per-token combine: invq, invk, g ----------------
__global__ __launch_bounds__(256) void k_normc(const float* __restrict__ psqQ,
                                               const float* __restrict__ psqK,
                                               const float* __restrict__ gdo,
                                               float* __restrict__ invqA,
                                               float* __restrict__ invkA,
                                               float* __restrict__ gA) {
  const int tkn = blockIdx.x * 256 + threadIdx.x;
  if (tkn >= MTOT) return;
  float sq = 0.f, sk = 0.f, gd = 0.f;
  #pragma unroll
  for (int cg = 0; cg < 8; ++cg) {
    sq += psqQ[(size_t)cg * MTOT + tkn];
    sk += psqK[(size_t)cg * MTOT + tkn];
    gd += gdo[(size_t)cg * MTOT + tkn];
  }
  float invq = 1.f / fmaxf(sqrtf(sq), EPSN);
  float invk = 1.f / fmaxf(sqrtf(sk), EPSN);
  invqA[tkn] = invq;
  invkA[tkn] = invk;
  gA[tkn]    = gd * invq;
}

// ---------------- qraw <- qraw * invq (in-place; regenerated every launch) ----------------
__global__ __launch_bounds__(512) void k_scaleQ(__bf16* __restrict__ qraw,
                                                const float* __restrict__ invqA) {
  const int b = blockIdx.y;
  const int chunk = blockIdx.x * 512 + threadIdx.x;   // 98*512 = 50176 = 784 rows * 64
  const int row = chunk >> 6;
  const int c8 = (chunk & 63) * 8;
  const size_t token = (size_t)b * 784 + row;
  __bf16* p = qraw + token * 512 + c8;
  const float s = invqA[token];
  bf16x8 v = *(const bf16x8*)p;
  #pragma unroll
  for (int j = 0; j < 8; ++j) v[j] = (__bf16)((float)v[j] * s);
  *(bf16x8*)p = v;
}

// ---------------- per-batch: ||g|| + ctx[d] = alpha * sum_n g[n]*Qn[n,d] ----------------
__global__ __launch_bounds__(512) void k_pctx(const __bf16* __restrict__ qn,
                                              const float* __restrict__ gA,
                                              float* __restrict__ ctx) {
  __shared__ float wred[8];
  __shared__ float part[4][128];
  const int ch = blockIdx.x, b = blockIdx.y, t = threadIdx.x;
  const size_t base = (size_t)b * 784;
  float gsq;
  { float gv = gA[base + t]; gsq = gv * gv; }
  if (t + 512 < 784) { float gv = gA[base + t + 512]; gsq = fmaf(gv, gv, gsq); }
  gsq += __shfl_xor(gsq, 1);  gsq += __shfl_xor(gsq, 2);  gsq += __shfl_xor(gsq, 4);
  gsq += __shfl_xor(gsq, 8);  gsq += __shfl_xor(gsq, 16); gsq += __shfl_xor(gsq, 32);
  if ((t & 63) == 0) wred[t >> 6] = gsq;
  __syncthreads();
  float tot = 0.f;
  #pragma unroll
  for (int i = 0; i < 8; ++i) tot += wred[i];
  const float alpha = SCALE_F / fmaxf(sqrtf(tot) * SCALE_F, EPSN);
  const int dof = t & 127, s = t >> 7;
  const int nb = s * 196;
  const __bf16* qb = qn + (base + nb) * 512 + ch * 128 + dof;
  const float* cf = gA + base + nb;
  float a0 = 0.f, a1 = 0.f, a2 = 0.f, a3 = 0.f;
  for (int n = 0; n < 196; n += 4) {
    a0 = fmaf(cf[n],     (float)qb[(size_t)n * 512],       a0);
    a1 = fmaf(cf[n + 1], (float)qb[(size_t)(n + 1) * 512], a1);
    a2 = fmaf(cf[n + 2], (float)qb[(size_t)(n + 2) * 512], a2);
    a3 = fmaf(cf[n + 3], (float)qb[(size_t)(n + 3) * 512], a3);
  }
  part[s][dof] = (a0 + a1) + (a2 + a3);
  __syncthreads();
  if (t < 128) {
    float sum = part[0][t] + part[1][t] + part[2][t] + part[3][t];
    ctx[(size_t)b * 512 + ch * 128 + t] = alpha * sum;
  }
}

// ---------------- kraw <- kraw * invk * ctx[b]  (in-place) ----------------
__global__ __launch_bounds__(512) void k_scaleK(__bf16* __restrict__ kraw,
                                                const float* __restrict__ invkA,
                                                const float* __restrict__ ctx) {
  const int b = blockIdx.y;
  const int chunk = blockIdx.x * 512 + threadIdx.x;
  const int row = chunk >> 6;
  const int c8 = (chunk & 63) * 8;
  const size_t token = (size_t)b * 784 + row;
  __bf16* p = kraw + token * 512 + c8;
  const float s = invkA[token];
  f32x4 c0 = *(const f32x4*)(ctx + (size_t)b * 512 + c8);
  f32x4 c1 = *(const f32x4*)(ctx + (size_t)b * 512 + c8 + 4);
  bf16x8 v = *(const bf16x8*)p;
  #pragma unroll
  for (int j = 0; j < 4; ++j) {
    v[j]     = (__bf16)((float)v[j]     * s * c0[j]);
    v[4 + j] = (__bf16)((float)v[4 + j] * s * c1[j]);
  }
  *(bf16x8*)p = v;
}

// ---------------- final GEMM: out = ([Kc | Qn] @ WcT^T + bpf)^T, 100% gld16, ring-3 ----------------
__global__ __launch_bounds__(256, 3) void k_out(const __bf16* __restrict__ qn,
                                                const __bf16* __restrict__ kc,
                                                const __bf16* __restrict__ WcT,
                                                const float* __restrict__ bpf,
                                                float* __restrict__ out) {
  __shared__ __align__(1024) unsigned char stg[3][16384];   // As 8K | Bs 8K per buf
  const int t = threadIdx.x, l = t & 63, w = t >> 6;
  const int li = l & 15, lq = l >> 4;
  const int p = blockIdx.x;
  const int xq = p & 7, q2 = p >> 3;
  const int nt = q2 & 3;
  const int g = (q2 >> 2) * 8 + xq;       // 0..447
  const int b = g / 7, mt = g % 7;
  const int m0 = mt * 128;

  const int r0 = 2 * w, r1 = r0 + 1;
  int row0 = m0 + r0 * 16 + li; if (row0 > 783) row0 = 783;
  int row1 = m0 + r1 * 16 + li; if (row1 > 783) row1 = 783;
  const size_t tk0 = (size_t)b * 784 + row0, tk1 = (size_t)b * 784 + row1;
  const __bf16* ak0 = kc + tk0 * 512 + lq * 8;
  const __bf16* ak1 = kc + tk1 * 512 + lq * 8;
  const __bf16* aq0 = qn + tk0 * 512 + lq * 8;
  const __bf16* aq1 = qn + tk1 * 512 + lq * 8;
  const __bf16* wpB0 = WcT + (size_t)(nt * 128 + r0 * 16 + li) * 1024 + lq * 8;
  const __bf16* wpB1 = WcT + (size_t)(nt * 128 + r1 * 16 + li) * 1024 + lq * 8;

  f32x4 acc[4][4] = {};

  auto stage = [&](unsigned char* buf, int ks) {
    const int kk = ks > 31 ? 31 : ks;
    const int off = (kk & 15) * 32;
    const __bf16* s0 = (kk < 16) ? ak0 : aq0;
    const __bf16* s1 = (kk < 16) ? ak1 : aq1;
    gld16(s0 + off, buf + r0 * 1024);
    gld16(s1 + off, buf + r1 * 1024);
    gld16(wpB0 + kk * 32, buf + 8192 + r0 * 1024);
    gld16(wpB1 + kk * 32, buf + 8192 + r1 * 1024);
  };
  auto mstep = [&](const unsigned char* buf) {
    bf16x8 af[4];
    #pragma unroll
    for (int rb = 0; rb < 4; ++rb)
      af[rb] = *(const bf16x8*)(buf + ((w & 1) * 4 + rb) * 1024 + l * 16);
    #pragma unroll
    for (int cb = 0; cb < 4; ++cb) {
      bf16x8 bf = *(const bf16x8*)(buf + 8192 + ((w >> 1) * 4 + cb) * 1024 + l * 16);
      #pragma unroll
      for (int rb = 0; rb < 4; ++rb)
        acc[rb][cb] = __builtin_amdgcn_mfma_f32_16x16x32_bf16(af[rb], bf, acc[rb][cb], 0, 0, 0);
    }
  };

  unsigned char *bc = stg[0], *bn = stg[1], *bn2 = stg[2];
  stage(bc, 0); stage(bn, 1);                               // 8 ops in flight
  asm volatile("s_waitcnt vmcnt(4)" ::: "memory");          // tile 0 landed
  __builtin_amdgcn_s_barrier();
  __builtin_amdgcn_sched_barrier(0);
  #pragma unroll 1
  for (int ks = 0; ks < 32; ++ks) {
    stage(bn2, ks + 2);                      // issue tile k+2 (clamped tail)
    __builtin_amdgcn_sched_barrier(0);
    mstep(bc);                               // compute tile k
    asm volatile("s_waitcnt vmcnt(4)" ::: "memory");  // retire tile k+1; k+2 stays in flight
    __builtin_amdgcn_s_barrier();
    __builtin_amdgcn_sched_barrier(0);
    unsigned char* tmp = bc; bc = bn; bn = bn2; bn2 = tmp;
  }
  asm volatile("s_waitcnt vmcnt(0)" ::: "memory");

  const int colb = nt * 128 + (w >> 1) * 64;
  float bv[4];
  #pragma unroll
  for (int cb = 0; cb < 4; ++cb) bv[cb] = bpf[colb + cb * 16 + li];
  #pragma unroll
  for (int rb = 0; rb < 4; ++rb) {
    int nrow = m0 + (w & 1) * 64 + rb * 16 + lq * 4;
    if (nrow < 784) {
      #pragma unroll
      for (int cb = 0; cb < 4; ++cb) {
        f32x4 v;
        #pragma unroll
        for (int j = 0; j < 4; ++j) v[j] = acc[rb][cb][j] + bv[cb];
        *(f32x4*)&out[((size_t)b * 512 + colb + cb * 16 + li) * 784 + nrow] = v;
      }
    }
  }
}

extern "C" void kernel_launch(void* const* d_in, const int* in_sizes, int n_in,
                              void* d_out, int out_size, void* d_ws, size_t ws_size,
                              hipStream_t stream) {
  const float* x   = (const float*)d_in[0];
  const float* Wq  = (const float*)d_in[1];
  const float* bq  = (const float*)d_in[2];
  const float* Wk  = (const float*)d_in[3];
  const float* bk  = (const float*)d_in[4];
  const float* wg  = (const float*)d_in[5];
  const float* Wp  = (const float*)d_in[6];
  const float* bp  = (const float*)d_in[7];
  const float* Wf  = (const float*)d_in[8];
  const float* bfv = (const float*)d_in[9];
  float* out = (float*)d_out;
  char* ws = (char*)d_ws;

  const size_t SZRAW = (size_t)MTOT * 512 * 2;        // 51,380,224 B
  const size_t SZXT  = (size_t)32 * 784 * 512 * 2;    // 25,690,112 B (one 32-batch slice)
  size_t off = 0;
  __bf16* qraw = (__bf16*)(ws + off); off += SZRAW;
  __bf16* kraw = (__bf16*)(ws + off); off += SZRAW;
  __bf16* xT   = (__bf16*)(ws + off); off += SZXT;
  __bf16* WqT  = (__bf16*)(ws + off); off += 524288;
  __bf16* WkT  = (__bf16*)(ws + off); off += 524288;
  __bf16* WcT  = (__bf16*)(ws + off); off += 1048576;
  float*  bpf  = (float*) (ws + off); off += 2048;
  float*  psqQ = (float*) (ws + off); off += (size_t)8 * MTOT * 4;
  float*  psqK = (float*) (ws + off); off += (size_t)8 * MTOT * 4;
  float*  gdo  = (float*) (ws + off); off += (size_t)8 * MTOT * 4;
  float*  invqA = (float*)(ws + off); off += (size_t)MTOT * 4;
  float*  invkA = (float*)(ws + off); off += (size_t)MTOT * 4;
  float*  gA    = (float*)(ws + off); off += (size_t)MTOT * 4;
  float*  ctx   = (float*)(ws + off); off += 131072;
  // total ~136 MB

  k_prep_t<<<dim3(16, 16), dim3(32, 8), 0, stream>>>(Wq, Wk, WqT, WkT);
  k_prep_w<<<dim3(256),    dim3(512),   0, stream>>>(Wp, Wf, bp, bfv, WcT, bpf);
  for (int s = 0; s < 2; ++s) {
    k_xt  <<<dim3(25, 16, 32), dim3(32, 8), 0, stream>>>(x, xT, s * 32);
    k_gemm<<<dim3(896),        dim3(256),   0, stream>>>(xT, WqT, WkT, bq, bk, wg, s * 32,
                                                         qraw, kraw, psqQ, psqK, gdo);
  }
  k_normc <<<dim3(196),    dim3(256), 0, stream>>>(psqQ, psqK, gdo, invqA, invkA, gA);
  k_scaleQ<<<dim3(98, 64), dim3(512), 0, stream>>>(qraw, invqA);
  k_pctx  <<<dim3(4, 64),  dim3(512), 0, stream>>>(qraw, gA, ctx);
  k_scaleK<<<dim3(98, 64), dim3(512), 0, stream>>>(kraw, invkA, ctx);
  k_out   <<<dim3(1792),   dim3(256), 0, stream>>>(qraw, kraw, WcT, bpf, out);
}

// Round 13
// 399.560 us; speedup vs baseline: 1.0548x; 1.0548x over previous
//
#include <hip/hip_runtime.h>

#define EPSN 1e-12f
#define SCALE_F 0.044194173824159216f  // 512^-0.5
#define MTOT 50176

typedef __bf16 bf16x8 __attribute__((ext_vector_type(8)));
typedef float  f32x4  __attribute__((ext_vector_type(4)));

__device__ __forceinline__ void gld16(const void* src, void* dst) {
  __builtin_amdgcn_global_load_lds(
      (const __attribute__((address_space(1))) unsigned int*)src,
      (__attribute__((address_space(3))) unsigned int*)dst, 16, 0, 0);
}

// ---------------- prep: xT[b][n][c] = bf16(x[b][c][n]) ----------------
__global__ __launch_bounds__(256) void k_xt(const float* __restrict__ x,
                                            __bf16* __restrict__ xT) {
  __shared__ float T[32][33];
  const int n0 = blockIdx.x * 32, c0 = blockIdx.y * 32;
  const int b = blockIdx.z;
  const int dx = threadIdx.x, ty = threadIdx.y;   // 32, 8
  #pragma unroll
  for (int pp = 0; pp < 4; ++pp) {
    int c = ty + pp * 8;
    int n = n0 + dx;
    T[c][dx] = (n < 784) ? x[((size_t)b * 512 + c0 + c) * 784 + n] : 0.f;
  }
  __syncthreads();
  #pragma unroll
  for (int pp = 0; pp < 4; ++pp) {
    int n = ty + pp * 8;
    if (n0 + n < 784)
      xT[((size_t)b * 784 + n0 + n) * 512 + c0 + dx] = (__bf16)T[dx][n];
  }
}

// ---------------- prep: WqT/WkT bf16 [d][c] = W[c][d], LDS tile transpose ----------------
__global__ __launch_bounds__(256) void k_prep_t(const float* __restrict__ Wq,
                                                const float* __restrict__ Wk,
                                                __bf16* __restrict__ WqT,
                                                __bf16* __restrict__ WkT) {
  __shared__ float Tq[32][33], Tk[32][33];
  const int c0 = blockIdx.x * 32, d0 = blockIdx.y * 32;
  const int dx = threadIdx.x, cy = threadIdx.y;  // 32, 8
  #pragma unroll
  for (int p = 0; p < 4; ++p) {
    int c = cy + p * 8;
    Tq[c][dx] = Wq[(size_t)(c0 + c) * 512 + d0 + dx];
    Tk[c][dx] = Wk[(size_t)(c0 + c) * 512 + d0 + dx];
  }
  __syncthreads();
  #pragma unroll
  for (int p = 0; p < 4; ++p) {
    int d = cy + p * 8;
    WqT[(size_t)(d0 + d) * 512 + c0 + dx] = (__bf16)Tq[dx][d];
    WkT[(size_t)(d0 + d) * 512 + c0 + dx] = (__bf16)Tk[dx][d];
  }
}

// ---- prep: WcT[d][kk]: kk<512 -> (Wp@Wf)[kk][d]; kk>=512 -> Wf[kk-512][d]. bpf[d]=bp@Wf+bf
__global__ __launch_bounds__(512) void k_prep_w(const float* __restrict__ Wp,
                                                const float* __restrict__ Wf,
                                                const float* __restrict__ bp,
                                                const float* __restrict__ bfv,
                                                __bf16* __restrict__ WcT,
                                                float* __restrict__ bpf) {
  const int kk0 = blockIdx.x * 2;
  const int d = threadIdx.x;
  float acc0 = 0.f, acc1 = 0.f, bacc = 0.f;
  const bool dobp = (blockIdx.x == 0);
  for (int c = 0; c < 512; ++c) {
    float wf = Wf[(size_t)c * 512 + d];
    acc0 = fmaf(Wp[(size_t)kk0 * 512 + c],       wf, acc0);
    acc1 = fmaf(Wp[(size_t)(kk0 + 1) * 512 + c], wf, acc1);
    if (dobp) bacc = fmaf(bp[c], wf, bacc);
  }
  WcT[(size_t)d * 1024 + kk0]           = (__bf16)acc0;
  WcT[(size_t)d * 1024 + kk0 + 1]       = (__bf16)acc1;
  WcT[(size_t)d * 1024 + 512 + kk0]     = (__bf16)Wf[(size_t)kk0 * 512 + d];
  WcT[(size_t)d * 1024 + 512 + kk0 + 1] = (__bf16)Wf[(size_t)(kk0 + 1) * 512 + d];
  if (dobp) bpf[d] = bacc + bfv[d];
}

// ---------------- Q or K GEMM (split): 128x128, pure gld16, RING-3 depth-2 ----------------
__global__ __launch_bounds__(256, 3) void k_gemm(const __bf16* __restrict__ xT,
                                                 const __bf16* __restrict__ WqT,
                                                 const __bf16* __restrict__ WkT,
                                                 const float* __restrict__ bq,
                                                 const float* __restrict__ bk,
                                                 const float* __restrict__ wg,
                                                 __bf16* __restrict__ qraw,
                                                 __bf16* __restrict__ kraw,
                                                 float* __restrict__ psqQ,
                                                 float* __restrict__ psqK,
                                                 float* __restrict__ gdo) {
  __shared__ __align__(1024) unsigned char stg[3][16384];   // As 8K | Bs 8K per buf
  const int t = threadIdx.x, l = t & 63, w = t >> 6;
  const int li = l & 15, lq = l >> 4;
  // decode XCD-swizzled id: p = ((g>>3)*8 + m)*8 + (g&7), m = qk*4+nt
  const int p = blockIdx.x;
  const int xq = p & 7, q2 = p >> 3;
  const int m8 = q2 & 7;
  const int g = (q2 >> 3) * 8 + xq;       // 0..447
  const int b = g / 7, mt = g % 7;
  const int qk = m8 >> 2, nt = m8 & 3;
  const int m0 = mt * 128;
  const __bf16* Wt = qk ? WkT : WqT;

  const int r0 = 2 * w, r1 = r0 + 1;
  int row0 = m0 + r0 * 16 + li; if (row0 > 783) row0 = 783;
  int row1 = m0 + r1 * 16 + li; if (row1 > 783) row1 = 783;
  const __bf16* a0s = xT + ((size_t)b * 784 + row0) * 512 + lq * 8;
  const __bf16* a1s = xT + ((size_t)b * 784 + row1) * 512 + lq * 8;
  const __bf16* w0s = Wt + (size_t)(nt * 128 + r0 * 16 + li) * 512 + lq * 8;
  const __bf16* w1s = Wt + (size_t)(nt * 128 + r1 * 16 + li) * 512 + lq * 8;

  f32x4 acc[4][4] = {};

  auto stage = [&](unsigned char* buf, int ks) {
    const int kk = (ks > 15 ? 15 : ks) * 32;
    gld16(a0s + kk, buf + r0 * 1024);
    gld16(a1s + kk, buf + r1 * 1024);
    gld16(w0s + kk, buf + 8192 + r0 * 1024);
    gld16(w1s + kk, buf + 8192 + r1 * 1024);
  };
  auto mstep = [&](const unsigned char* buf) {
    bf16x8 af[4];
    #pragma unroll
    for (int rb = 0; rb < 4; ++rb)
      af[rb] = *(const bf16x8*)(buf + ((w & 1) * 4 + rb) * 1024 + l * 16);
    #pragma unroll
    for (int cb = 0; cb < 4; ++cb) {
      bf16x8 bf = *(const bf16x8*)(buf + 8192 + ((w >> 1) * 4 + cb) * 1024 + l * 16);
      #pragma unroll
      for (int rb = 0; rb < 4; ++rb)
        acc[rb][cb] = __builtin_amdgcn_mfma_f32_16x16x32_bf16(af[rb], bf, acc[rb][cb], 0, 0, 0);
    }
  };

  unsigned char *bc = stg[0], *bn = stg[1], *bn2 = stg[2];
  stage(bc, 0); stage(bn, 1);                               // 8 ops in flight
  asm volatile("s_waitcnt vmcnt(4)" ::: "memory");          // tile 0 landed
  __builtin_amdgcn_s_barrier();
  __builtin_amdgcn_sched_barrier(0);
  #pragma unroll 1
  for (int ks = 0; ks < 16; ++ks) {
    stage(bn2, ks + 2);
    __builtin_amdgcn_sched_barrier(0);
    mstep(bc);
    asm volatile("s_waitcnt vmcnt(4)" ::: "memory");        // retire tile k+1; k+2 in flight
    __builtin_amdgcn_s_barrier();
    __builtin_amdgcn_sched_barrier(0);
    unsigned char* tmp = bc; bc = bn; bn = bn2; bn2 = tmp;
  }
  asm volatile("s_waitcnt vmcnt(0)" ::: "memory");

  // epilogue: bias, raw store, per-colgroup partial sumsq (+ gdot for Q)
  const float* bias = qk ? bk : bq;
  __bf16* dst = qk ? kraw : qraw;
  float* psq = qk ? psqK : psqQ;
  const int colb = nt * 128 + (w >> 1) * 64;
  const int cg = nt * 2 + (w >> 1);
  float bv[4], wv[4];
  #pragma unroll
  for (int cb = 0; cb < 4; ++cb) {
    int col = colb + cb * 16 + li;
    bv[cb] = bias[col];
    wv[cb] = qk ? 0.f : wg[col];
  }
  #pragma unroll
  for (int rb = 0; rb < 4; ++rb)
    #pragma unroll
    for (int j = 0; j < 4; ++j) {
      int rowg = m0 + (w & 1) * 64 + rb * 16 + lq * 4 + j;
      bool ok = rowg < 784;
      size_t token = (size_t)b * 784 + rowg;
      float ss = 0.f, sg = 0.f;
      #pragma unroll
      for (int cb = 0; cb < 4; ++cb) {
        float v = acc[rb][cb][j] + bv[cb];
        ss = fmaf(v, v, ss);
        sg = fmaf(v, wv[cb], sg);
        if (ok) dst[token * 512 + colb + cb * 16 + li] = (__bf16)v;
      }
      ss += __shfl_xor(ss, 1); ss += __shfl_xor(ss, 2); ss += __shfl_xor(ss, 4); ss += __shfl_xor(ss, 8);
      sg += __shfl_xor(sg, 1); sg += __shfl_xor(sg, 2); sg += __shfl_xor(sg, 4); sg += __shfl_xor(sg, 8);
      if (ok && li == 0) {
        psq[(size_t)cg * MTOT + token] = ss;
        if (!qk) gdo[(size_t)cg * MTOT + token] = sg;
      }
    }
}

// ---------------- per-token combine: invq, ratio=||q||/||k||, coef, g ----------------
__global__ __launch_bounds__(256) void k_normc(const float* __restrict__ psqQ,
                                               const float* __restrict__ psqK,
                                               const float* __restrict__ gdo,
                                               float* __restrict__ invqA,
                                               float* __restrict__ ratioA,
                                               float* __restrict__ coefA,
                                               float* __restrict__ gA) {
  const int tkn = blockIdx.x * 256 + threadIdx.x;
  if (tkn >= MTOT) return;
  float sq = 0.f, sk = 0.f, gd = 0.f;
  #pragma unroll
  for (int cg = 0; cg < 8; ++cg) {
    sq += psqQ[(size_t)cg * MTOT + tkn];
    sk += psqK[(size_t)cg * MTOT + tkn];
    gd += gdo[(size_t)cg * MTOT + tkn];
  }
  float nq = fmaxf(sqrtf(sq), EPSN);
  float nk = fmaxf(sqrtf(sk), EPSN);
  float invq = 1.f / nq;
  float gv = gd * invq;
  invqA[tkn]  = invq;
  ratioA[tkn] = nq / nk;          // (1/nk)/(1/nq)
  coefA[tkn]  = gv * invq;        // applied to RAW qraw in pctx
  gA[tkn]     = gv;
}

// ---------------- per-batch: ||g|| + ctx[d] = alpha * sum_n coef[n]*qraw[n,d] ----------------
__global__ __launch_bounds__(512) void k_pctx(const __bf16* __restrict__ qraw,
                                              const float* __restrict__ coefA,
                                              const float* __restrict__ gA,
                                              float* __restrict__ ctx) {
  __shared__ float wred[8];
  __shared__ float part[4][128];
  const int ch = blockIdx.x, b = blockIdx.y, t = threadIdx.x;
  const size_t base = (size_t)b * 784;
  float gsq;
  { float gv = gA[base + t]; gsq = gv * gv; }
  if (t + 512 < 784) { float gv = gA[base + t + 512]; gsq = fmaf(gv, gv, gsq); }
  gsq += __shfl_xor(gsq, 1);  gsq += __shfl_xor(gsq, 2);  gsq += __shfl_xor(gsq, 4);
  gsq += __shfl_xor(gsq, 8);  gsq += __shfl_xor(gsq, 16); gsq += __shfl_xor(gsq, 32);
  if ((t & 63) == 0) wred[t >> 6] = gsq;
  __syncthreads();
  float tot = 0.f;
  #pragma unroll
  for (int i = 0; i < 8; ++i) tot += wred[i];
  const float alpha = SCALE_F / fmaxf(sqrtf(tot) * SCALE_F, EPSN);
  const int dof = t & 127, s = t >> 7;
  const int nb = s * 196;
  const __bf16* qb = qraw + (base + nb) * 512 + ch * 128 + dof;
  const float* cf = coefA + base + nb;
  float a0 = 0.f, a1 = 0.f, a2 = 0.f, a3 = 0.f;
  for (int n = 0; n < 196; n += 4) {
    a0 = fmaf(cf[n],     (float)qb[(size_t)n * 512],       a0);
    a1 = fmaf(cf[n + 1], (float)qb[(size_t)(n + 1) * 512], a1);
    a2 = fmaf(cf[n + 2], (float)qb[(size_t)(n + 2) * 512], a2);
    a3 = fmaf(cf[n + 3], (float)qb[(size_t)(n + 3) * 512], a3);
  }
  part[s][dof] = (a0 + a1) + (a2 + a3);
  __syncthreads();
  if (t < 128) {
    float sum = part[0][t] + part[1][t] + part[2][t] + part[3][t];
    ctx[(size_t)b * 512 + ch * 128 + t] = alpha * sum;
  }
}

// ---------------- Bc[b][d][k] = bf16(ctx[b][k] * Wpf[k][d])  (K-half of WcT) ----------------
__global__ __launch_bounds__(256) void k_wcb(const __bf16* __restrict__ WcT,
                                             const float* __restrict__ ctx,
                                             __bf16* __restrict__ Bc) {
  const int b = blockIdx.y;
  const int idx = (blockIdx.x * 256 + threadIdx.x) * 8;   // 128 blocks * 2048 elems
  const int d = idx >> 9, k = idx & 511;
  bf16x8 wv = *(const bf16x8*)(WcT + (size_t)d * 1024 + k);
  f32x4 c0 = *(const f32x4*)(ctx + (size_t)b * 512 + k);
  f32x4 c1 = *(const f32x4*)(ctx + (size_t)b * 512 + k + 4);
  bf16x8 r;
  #pragma unroll
  for (int j = 0; j < 4; ++j) {
    r[j]     = (__bf16)((float)wv[j]     * c0[j]);
    r[4 + j] = (__bf16)((float)wv[4 + j] * c1[j]);
  }
  *(bf16x8*)(Bc + ((size_t)b << 18) + idx) = r;
}

// ---------------- final GEMM: out = (1/||k||)*(kraw@Bc) + invq*(qraw@Wf) + bpf, transposed store
// Pure gld16 ring-3; acc *= ratio at K->Q transition; epilogue *= invq.
__global__ __launch_bounds__(256, 3) void k_out(const __bf16* __restrict__ qraw,
                                                const __bf16* __restrict__ kraw,
                                                const __bf16* __restrict__ Bc,
                                                const __bf16* __restrict__ WcT,
                                                const float* __restrict__ invqA,
                                                const float* __restrict__ ratioA,
                                                const float* __restrict__ bpf,
                                                float* __restrict__ out) {
  __shared__ __align__(1024) unsigned char stg[3][16384];   // As 8K | Bs 8K per buf
  const int t = threadIdx.x, l = t & 63, w = t >> 6;
  const int li = l & 15, lq = l >> 4;
  const int p = blockIdx.x;
  const int xq = p & 7, q2 = p >> 3;
  const int nt = q2 & 3;
  const int g = (q2 >> 2) * 8 + xq;       // 0..447
  const int b = g / 7, mt = g % 7;
  const int m0 = mt * 128;

  const int r0 = 2 * w, r1 = r0 + 1;
  int row0 = m0 + r0 * 16 + li; if (row0 > 783) row0 = 783;
  int row1 = m0 + r1 * 16 + li; if (row1 > 783) row1 = 783;
  const size_t tk0 = (size_t)b * 784 + row0, tk1 = (size_t)b * 784 + row1;
  const __bf16* ak0 = kraw + tk0 * 512 + lq * 8;
  const __bf16* ak1 = kraw + tk1 * 512 + lq * 8;
  const __bf16* aq0 = qraw + tk0 * 512 + lq * 8;
  const __bf16* aq1 = qraw + tk1 * 512 + lq * 8;
  const __bf16* bc0 = Bc + ((size_t)b << 18) + (size_t)(nt * 128 + r0 * 16 + li) * 512 + lq * 8;
  const __bf16* bc1 = Bc + ((size_t)b << 18) + (size_t)(nt * 128 + r1 * 16 + li) * 512 + lq * 8;
  const __bf16* wp0 = WcT + (size_t)(nt * 128 + r0 * 16 + li) * 1024 + lq * 8;
  const __bf16* wp1 = WcT + (size_t)(nt * 128 + r1 * 16 + li) * 1024 + lq * 8;

  // per-row scale factors for this lane's 16 acc rows
  float ratio16[16], invq16[16];
  #pragma unroll
  for (int rb = 0; rb < 4; ++rb)
    #pragma unroll
    for (int j = 0; j < 4; ++j) {
      int rowg = m0 + (w & 1) * 64 + rb * 16 + lq * 4 + j;
      if (rowg > 783) rowg = 783;
      size_t token = (size_t)b * 784 + rowg;
      ratio16[rb * 4 + j] = ratioA[token];
      invq16[rb * 4 + j]  = invqA[token];
    }

  f32x4 acc[4][4] = {};

  auto stage = [&](unsigned char* buf, int ks) {
    const int kk = ks > 31 ? 31 : ks;
    const int off = (kk & 15) * 32;
    if (kk < 16) {
      gld16(ak0 + off, buf + r0 * 1024);
      gld16(ak1 + off, buf + r1 * 1024);
      gld16(bc0 + off, buf + 8192 + r0 * 1024);
      gld16(bc1 + off, buf + 8192 + r1 * 1024);
    } else {
      gld16(aq0 + off, buf + r0 * 1024);
      gld16(aq1 + off, buf + r1 * 1024);
      gld16(wp0 + kk * 32, buf + 8192 + r0 * 1024);   // kk*32 >= 512 -> Wf half
      gld16(wp1 + kk * 32, buf + 8192 + r1 * 1024);
    }
  };
  auto mstep = [&](const unsigned char* buf) {
    bf16x8 af[4];
    #pragma unroll
    for (int rb = 0; rb < 4; ++rb)
      af[rb] = *(const bf16x8*)(buf + ((w & 1) * 4 + rb) * 1024 + l * 16);
    #pragma unroll
    for (int cb = 0; cb < 4; ++cb) {
      bf16x8 bf = *(const bf16x8*)(buf + 8192 + ((w >> 1) * 4 + cb) * 1024 + l * 16);
      #pragma unroll
      for (int rb = 0; rb < 4; ++rb)
        acc[rb][cb] = __builtin_amdgcn_mfma_f32_16x16x32_bf16(af[rb], bf, acc[rb][cb], 0, 0, 0);
    }
  };

  unsigned char *bc_ = stg[0], *bn = stg[1], *bn2 = stg[2];
  stage(bc_, 0); stage(bn, 1);
  asm volatile("s_waitcnt vmcnt(4)" ::: "memory");
  __builtin_amdgcn_s_barrier();
  __builtin_amdgcn_sched_barrier(0);
  #pragma unroll 1
  for (int ks = 0; ks < 16; ++ks) {          // K-half
    stage(bn2, ks + 2);
    __builtin_amdgcn_sched_barrier(0);
    mstep(bc_);
    asm volatile("s_waitcnt vmcnt(4)" ::: "memory");
    __builtin_amdgcn_s_barrier();
    __builtin_amdgcn_sched_barrier(0);
    unsigned char* tmp = bc_; bc_ = bn; bn = bn2; bn2 = tmp;
  }
  // transition: acc holds K-part; scale by ratio = ||q||/||k|| (register-only)
  #pragma unroll
  for (int rb = 0; rb < 4; ++rb)
    #pragma unroll
    for (int cb = 0; cb < 4; ++cb)
      #pragma unroll
      for (int j = 0; j < 4; ++j)
        acc[rb][cb][j] *= ratio16[rb * 4 + j];
  #pragma unroll 1
  for (int ks = 16; ks < 32; ++ks) {         // Q-half
    stage(bn2, ks + 2);
    __builtin_amdgcn_sched_barrier(0);
    mstep(bc_);
    asm volatile("s_waitcnt vmcnt(4)" ::: "memory");
    __builtin_amdgcn_s_barrier();
    __builtin_amdgcn_sched_barrier(0);
    unsigned char* tmp = bc_; bc_ = bn; bn = bn2; bn2 = tmp;
  }
  asm volatile("s_waitcnt vmcnt(0)" ::: "memory");

  const int colb = nt * 128 + (w >> 1) * 64;
  float bv[4];
  #pragma unroll
  for (int cb = 0; cb < 4; ++cb) bv[cb] = bpf[colb + cb * 16 + li];
  #pragma unroll
  for (int rb = 0; rb < 4; ++rb) {
    int nrow = m0 + (w & 1) * 64 + rb * 16 + lq * 4;
    if (nrow < 784) {
      #pragma unroll
      for (int cb = 0; cb < 4; ++cb) {
        f32x4 v;
        #pragma unroll
        for (int j = 0; j < 4; ++j)
          v[j] = acc[rb][cb][j] * invq16[rb * 4 + j] + bv[cb];
        *(f32x4*)&out[((size_t)b * 512 + colb + cb * 16 + li) * 784 + nrow] = v;
      }
    }
  }
}

extern "C" void kernel_launch(void* const* d_in, const int* in_sizes, int n_in,
                              void* d_out, int out_size, void* d_ws, size_t ws_size,
                              hipStream_t stream) {
  const float* x   = (const float*)d_in[0];
  const float* Wq  = (const float*)d_in[1];
  const float* bq  = (const float*)d_in[2];
  const float* Wk  = (const float*)d_in[3];
  const float* bk  = (const float*)d_in[4];
  const float* wg  = (const float*)d_in[5];
  const float* Wp  = (const float*)d_in[6];
  const float* bp  = (const float*)d_in[7];
  const float* Wf  = (const float*)d_in[8];
  const float* bfv = (const float*)d_in[9];
  float* out = (float*)d_out;
  char* ws = (char*)d_ws;

  const size_t SZRAW = (size_t)MTOT * 512 * 2;        // 51,380,224 B
  size_t off = 0;
  __bf16* qraw = (__bf16*)(ws + off); off += SZRAW;
  __bf16* kraw = (__bf16*)(ws + off); off += SZRAW;
  __bf16* xT   = (__bf16*)(ws + off); off += SZRAW;   // Bc (33.5 MB) aliases this (xT dead)
  __bf16* Bc   = xT;
  __bf16* WqT  = (__bf16*)(ws + off); off += 524288;
  __bf16* WkT  = (__bf16*)(ws + off); off += 524288;
  __bf16* WcT  = (__bf16*)(ws + off); off += 1048576;
  float*  bpf  = (float*) (ws + off); off += 2048;
  float*  psqQ = (float*) (ws + off); off += (size_t)8 * MTOT * 4;
  float*  psqK = (float*) (ws + off); off += (size_t)8 * MTOT * 4;
  float*  gdo  = (float*) (ws + off); off += (size_t)8 * MTOT * 4;
  float*  invqA  = (float*)(ws + off); off += (size_t)MTOT * 4;
  float*  ratioA = (float*)(ws + off); off += (size_t)MTOT * 4;
  float*  coefA  = (float*)(ws + off); off += (size_t)MTOT * 4;
  float*  gA     = (float*)(ws + off); off += (size_t)MTOT * 4;
  float*  ctx    = (float*)(ws + off); off += 131072;
  // total ~162 MB

  k_prep_t<<<dim3(16, 16),     dim3(32, 8), 0, stream>>>(Wq, Wk, WqT, WkT);
  k_prep_w<<<dim3(256),        dim3(512),   0, stream>>>(Wp, Wf, bp, bfv, WcT, bpf);
  k_xt    <<<dim3(25, 16, 64), dim3(32, 8), 0, stream>>>(x, xT);
  k_gemm  <<<dim3(3584),       dim3(256),   0, stream>>>(xT, WqT, WkT, bq, bk, wg,
                                                         qraw, kraw, psqQ, psqK, gdo);
  k_normc <<<dim3(196),        dim3(256),   0, stream>>>(psqQ, psqK, gdo, invqA, ratioA, coefA, gA);
  k_pctx  <<<dim3(4, 64),      dim3(512),   0, stream>>>(qraw, coefA, gA, ctx);
  k_wcb   <<<dim3(128, 64),    dim3(256),   0, stream>>>(WcT, ctx, Bc);
  k_out   <<<dim3(1792),       dim3(256),   0, stream>>>(qraw, kraw, Bc, WcT, invqA, ratioA,
                                                         bpf, out);
}